// Round 11
// baseline (49.953 us; speedup 1.0000x reference)
//
#include <hip/hip_runtime.h>

// ResidualVQ forward: out[n] = codebook[argmin_k(-2 x.c_k + ||c_k||^2)]
// v11: v10's barrier-free L2-direct MFMA datapath + LDS/atomic-FREE hot
// epilogue: running row-min in a register, append block branch-skipped via
// __any (appends only on running-min improvement / near-margin ties).
// v7-v10 flaw fixed: tile-min no longer force-appends every tile (that was
// ~16 serialized same-address LDS atomics + rmin round-trip per wave-tile,
// the invisible DS-pipe serializer behind the stubborn ~42-47 us).

typedef short bfrag __attribute__((ext_vector_type(8)));  // 8 bf16 = 4 VGPR
typedef float f32x4 __attribute__((ext_vector_type(4)));

constexpr int D = 128;      // embedding dim
constexpr int BR = 32;      // rows per block -> grid 1024 = 4 blocks/CU
constexpr int NTH = 256;    // 4 waves: 2 row-groups (16 rows) x 2 K-halves
constexpr int LCAP = 1024;  // candidate capacity per block (expect ~200)
#define MARGIN 3.25f        // > 2 * max |approx dist err| (x split; cb bf16)

__device__ __forceinline__ unsigned fenc(float f) {  // order-preserving f32->u32
    unsigned u = __float_as_uint(f);
    return (u & 0x80000000u) ? ~u : (u | 0x80000000u);
}
__device__ __forceinline__ unsigned cvtpk(float a, float b) {
    unsigned r;
    asm("v_cvt_pk_bf16_f32 %0, %1, %2" : "=v"(r) : "v"(a), "v"(b));
    return r;
}
union FU { bfrag v; unsigned u[4]; };

// 8 fp32 -> bf16 hi fragment + bf16 lo (residual) fragment
__device__ __forceinline__ void conv8(const float* f, bfrag& hi, bfrag& lo) {
    FU h, l;
#pragma unroll
    for (int m = 0; m < 4; ++m) {
        float a = f[2 * m], b = f[2 * m + 1];
        unsigned hp = cvtpk(a, b);
        float ra = a - __uint_as_float(hp << 16);
        float rb = b - __uint_as_float(hp & 0xFFFF0000u);
        h.u[m] = hp;
        l.u[m] = cvtpk(ra, rb);
    }
    hi = h.v;
    lo = l.v;
}

// --- prep: exact cnorm (K threads) + bf16 fragment cast (K*16 threads) ---
// Fragment t (= cg*256 + ks*64 + lane, lane=kg*16+la) holds
// cb[cg*16+la][ks*32+kg*8 .. +7], bf16 RN. Coalesced 16B writes.
__global__ __launch_bounds__(256) void prep_kernel(const float* __restrict__ cb,
                                                   float* __restrict__ cnorm,
                                                   short* __restrict__ hi, int K) {
    const int tg = blockIdx.x * 256 + threadIdx.x;  // 0..16383
    {
        const int cg = tg >> 8;
        const int r = tg & 255;
        const int ks = r >> 6;
        const int lane = r & 63;
        const int kg = lane >> 4, la = lane & 15;
        const float* src = cb + (size_t)(cg * 16 + la) * D + ks * 32 + kg * 8;
        float4 f0 = *(const float4*)src;
        float4 f1 = *(const float4*)(src + 4);
        FU h;
        h.u[0] = cvtpk(f0.x, f0.y);
        h.u[1] = cvtpk(f0.z, f0.w);
        h.u[2] = cvtpk(f1.x, f1.y);
        h.u[3] = cvtpk(f1.z, f1.w);
        ((bfrag*)hi)[tg] = h.v;
    }
    if (tg < K) {
        const float4* c = (const float4*)(cb + (size_t)tg * D);
        float s0 = 0.f, s1 = 0.f, s2 = 0.f, s3 = 0.f;
#pragma unroll
        for (int i = 0; i < D / 4; ++i) {
            float4 v = c[i];
            s0 = fmaf(v.x, v.x, s0);
            s1 = fmaf(v.y, v.y, s1);
            s2 = fmaf(v.z, v.z, s2);
            s3 = fmaf(v.w, v.w, s3);
        }
        cnorm[tg] = (s0 + s1) + (s2 + s3);
    }
}

__global__ __launch_bounds__(NTH, 4) void vq_mfma(const float* __restrict__ x,
                                                  const float* __restrict__ cb,
                                                  const short* __restrict__ cbh,
                                                  const float* __restrict__ cnorm,
                                                  float* __restrict__ out,
                                                  int N, int K) {
    __shared__ float cns[1024];          // 4 KB
    __shared__ unsigned clist[LCAP];     // 4 KB
    __shared__ unsigned long long win[BR];
    __shared__ int ccnt;
    // ~8.5 KB LDS; 4 blocks/CU (grid-limited), 16 waves/CU at VGPR<=128

    const int tid = threadIdx.x;
    const int lane = tid & 63;
    const int wv = tid >> 6;   // 0..3
    const int rg = wv >> 1;    // row-group (16 rows)
    const int khw = wv & 1;    // K half (512 codes) this wave covers
    const int la = lane & 15;
    const int kg = lane >> 4;
    const int row0 = blockIdx.x * BR;

    if (tid < BR) win[tid] = ~0ull;
    if (tid == 0) ccnt = 0;
    for (int i = tid; i < K; i += NTH) cns[i] = cnorm[i];

    // ---- (-2x) -> split-bf16 B-fragments in registers (col=la=row, k=kg*8+j) ----
    bfrag xh[4], xl[4];
    {
        const int xrow = row0 + rg * 16 + la;
        const float* xp = x + (size_t)xrow * D + kg * 8;
#pragma unroll
        for (int ks = 0; ks < 4; ++ks) {
            float4 f0 = *(const float4*)(xp + ks * 32);
            float4 f1 = *(const float4*)(xp + ks * 32 + 4);
            float v[8] = {-2.f * f0.x, -2.f * f0.y, -2.f * f0.z, -2.f * f0.w,
                          -2.f * f1.x, -2.f * f1.y, -2.f * f1.z, -2.f * f1.w};
            conv8(v, xh[ks], xl[ks]);
        }
    }
    __syncthreads();  // ccnt/win/cns ready before any appends

    // per-lane fragment pointer for this wave's K half (L2-resident, 256 KB)
    const bfrag* fpb = (const bfrag*)cbh + (size_t)khw * 8192 + lane;
    const int row = rg * 16 + la;  // block-local row this lane owns
    float rm = 3.4e38f;            // running approx row-min (REGISTER)

    auto load8 = [&](bfrag* dst, int tf) {  // tf = tile's fragment offset (t*512)
        const bfrag* p = fpb + tf;
#pragma unroll
        for (int cf = 0; cf < 2; ++cf)
#pragma unroll
            for (int ks = 0; ks < 4; ++ks)
                dst[cf * 4 + ks] = p[cf * 256 + ks * 64];  // global_load_dwordx4
    };

    auto compute = [&](const bfrag* f, int t) {  // one 32-code tile
        const int cbase = khw * 512 + t * 32;
        f32x4 acc[2];
        acc[0] = *(const f32x4*)&cns[cbase + kg * 4];        // cn folded in
        acc[1] = *(const f32x4*)&cns[cbase + 16 + kg * 4];
#pragma unroll
        for (int ks = 0; ks < 4; ++ks)
#pragma unroll
            for (int cf = 0; cf < 2; ++cf) {
                // swapped operands: A=codebook, B=x -> C[row=code][col=x-row]
                acc[cf] = __builtin_amdgcn_mfma_f32_16x16x32_bf16(
                    f[cf * 4 + ks], xh[ks], acc[cf], 0, 0, 0);
                acc[cf] = __builtin_amdgcn_mfma_f32_16x16x32_bf16(
                    f[cf * 4 + ks], xl[ks], acc[cf], 0, 0, 0);
            }
        // acc[cf][i] = dist(code cbase+cf*16+kg*4+i, row)
        float m = fminf(fminf(fminf(acc[0][0], acc[0][1]), fminf(acc[0][2], acc[0][3])),
                        fminf(fminf(acc[1][0], acc[1][1]), fminf(acc[1][2], acc[1][3])));
        m = fminf(m, __shfl_xor(m, 16));
        m = fminf(m, __shfl_xor(m, 32));  // min over this tile's 32 codes for `row`
        // append only when the tile approaches the running min (rare):
        // winner w satisfies approx(w) <= final_min + 2e <= rm + 2e < rm + MARGIN,
        // so the superset property holds; fmin(rm, m) bounds t=0 (rm = +inf).
        if (__any(m < rm + MARGIN)) {
            const float thr = fminf(rm, m) + MARGIN;
#pragma unroll
            for (int cf = 0; cf < 2; ++cf)
#pragma unroll
                for (int i = 0; i < 4; ++i) {
                    if (acc[cf][i] < thr) {
                        int p = atomicAdd(&ccnt, 1);
                        if (p < LCAP)
                            clist[p] = (unsigned)((row << 10)
                                                  | (cbase + cf * 16 + kg * 4 + i));
                    }
                }
        }
        rm = fminf(rm, m);
    };

    // ---- barrier-free K-loop: 16 tiles, register double-buffer ----
    bfrag cur[8], nxt[8];
    load8(cur, 0);
#pragma unroll 1
    for (int t = 0; t < 16; t += 2) {
        load8(nxt, (t + 1) * 512);   // in flight under compute(cur)
        compute(cur, t);
        if (t + 2 < 16) load8(cur, (t + 2) * 512);  // in flight under compute(nxt)
        compute(nxt, t + 1);
    }

    __syncthreads();  // all appends visible

    // ---- exact fp32 recheck; packed LDS atomicMin keeps lowest idx on ties ----
    const int nc = (ccnt > LCAP) ? LCAP : ccnt;
    for (int b = wv * 4 + kg; b < nc; b += 16) {  // one candidate per 16-lane group
        const unsigned e = clist[b];
        const int crow = e >> 10, code = e & 1023;
        const float4* xr4 = (const float4*)(x + (size_t)(row0 + crow) * D + la * 8);
        const float4* cr4 = (const float4*)(cb + (size_t)code * D + la * 8);
        float4 a0 = xr4[0], a1 = xr4[1], b0 = cr4[0], b1 = cr4[1];
        float s = a0.x * b0.x;
        s = fmaf(a0.y, b0.y, s); s = fmaf(a0.z, b0.z, s); s = fmaf(a0.w, b0.w, s);
        s = fmaf(a1.x, b1.x, s); s = fmaf(a1.y, b1.y, s);
        s = fmaf(a1.z, b1.z, s); s = fmaf(a1.w, b1.w, s);
#pragma unroll
        for (int off = 1; off <= 8; off <<= 1) s += __shfl_xor(s, off);
        const float dist = fmaf(-2.f, s, cns[code]);
        if (la == 0)
            atomicMin(&win[crow],
                      ((unsigned long long)fenc(dist) << 32) | (unsigned)code);
    }
    __syncthreads();

    // ---- gather: out[row] = cb[winner] (coalesced float4) ----
    {
        const int r = tid >> 3, q = tid & 7;  // 32 rows x 8 chunks of 16 floats
        const int idx = (int)(win[r] & 0xFFFFFFFFull);
        const float4* cs = (const float4*)(cb + (size_t)idx * D + q * 16);
        float4* od = (float4*)(out + (size_t)(row0 + r) * D + q * 16);
#pragma unroll
        for (int i = 0; i < 4; ++i) od[i] = cs[i];
    }
}

extern "C" void kernel_launch(void* const* d_in, const int* in_sizes, int n_in,
                              void* d_out, int out_size, void* d_ws, size_t ws_size,
                              hipStream_t stream) {
    const float* x = (const float*)d_in[0];
    const float* cb = (const float*)d_in[1];
    float* out = (float*)d_out;
    const int N = in_sizes[0] / D;   // 32768
    const int K = in_sizes[1] / D;   // 1024

    float* cnorm = (float*)d_ws;                   // 4 KB
    short* cbh = (short*)((char*)d_ws + 4096);     // 256 KB bf16 fragments

    hipLaunchKernelGGL(prep_kernel, dim3(K * 16 / 256), dim3(256), 0, stream,
                       cb, cnorm, cbh, K);
    hipLaunchKernelGGL(vq_mfma, dim3(N / BR), dim3(NTH), 0, stream,
                       x, cb, cbh, cnorm, out, N, K);
}